// Round 1
// baseline (108.130 us; speedup 1.0000x reference)
//
#include <hip/hip_runtime.h>
#include <hip/hip_bf16.h>

#define NTOK 64
#define CDIM 128

typedef __attribute__((ext_vector_type(4))) float  f32x4;
typedef __attribute__((ext_vector_type(8))) short  bf16x8;
typedef __attribute__((ext_vector_type(4))) short  s16x4;

__device__ __forceinline__ short f2bf(float f) {
  // RTNE fp32 -> bf16 (inputs finite)
  unsigned u = __float_as_uint(f);
  unsigned r = (u + 0x7fffu + ((u >> 16) & 1u)) >> 16;
  return (short)r;
}

__device__ __forceinline__ int swz(int row, int cb, int stride) {
  return row * stride + (cb ^ ((row & 7) << 4));
}

__global__ void wconv_kernel(const float* __restrict__ wq, const float* __restrict__ wk,
                             const float* __restrict__ wv, const float* __restrict__ wo,
                             short* __restrict__ wbf) {
  int t = blockIdx.x * 256 + threadIdx.x;   // 64 blocks * 256 = 16384 = 128*128
  wbf[t]         = f2bf(wq[t]);
  wbf[16384 + t] = f2bf(wk[t]);
  wbf[32768 + t] = f2bf(wv[t]);
  wbf[49152 + t] = f2bf(wo[t]);
}

// LDS byte offsets
#define XO_OFF   0        // 64 rows x 256B : X bf16 [i][c], later O [i][c]
#define Q_OFF    16384    // 64 x 256B : Q [i][d]
#define K_OFF    32768    // 64 x 256B : K [i][d]
#define P_OFF    16384    // P_h at P_OFF + h*8192 : [i][j], 64 x 128B (overwrites Q/K after barrier)
#define VT_OFF   49152    // 128 x 128B : Vt [d][i]
#define GATE_OFF 65536    // 64 floats
#define SMEM_BYTES (65536 + 256)

__global__ __launch_bounds__(256, 2) void fused_attn(
    const float* __restrict__ x, const float* __restrict__ ent,
    const short* __restrict__ wbf,
    const float* __restrict__ bq, const float* __restrict__ bk,
    const float* __restrict__ bv, const float* __restrict__ bo,
    const int* __restrict__ beta, float* __restrict__ out)
{
  __shared__ unsigned char sm[SMEM_BYTES];
  float* gate = (float*)(sm + GATE_OFF);
  const int tid  = threadIdx.x;
  const int lane = tid & 63;
  const int w    = tid >> 6;        // wave id 0..3 (= head id in attn phases)
  const int g    = lane >> 4;       // 16-lane group 0..3
  const int li   = lane & 15;
  const int b    = blockIdx.x;

  // ---------- phase 0: stage X (fp32 -> bf16, swizzled) + gate ----------
  {
    const float* xb = x + (size_t)b * (NTOK * CDIM);
    #pragma unroll
    for (int it = 0; it < 8; ++it) {
      int f = (tid + 256 * it) * 4;
      int row = f >> 7, col = f & 127;
      float4 v = *reinterpret_cast<const float4*>(xb + f);
      s16x4 pk;
      pk.x = f2bf(v.x); pk.y = f2bf(v.y); pk.z = f2bf(v.z); pk.w = f2bf(v.w);
      *reinterpret_cast<s16x4*>(sm + XO_OFF + swz(row, col * 2, 256)) = pk;
    }
    if (tid < NTOK) {
      float bf = (float)beta[0];
      gate[tid] = -bf * ent[(size_t)b * NTOK + tid];
    }
  }
  __syncthreads();

  // ---------- phase 1: projections ----------
  // Preload all X fragments: xf[t][k] usable both as B-op (QK swapped) and A-op (V normal)
  bf16x8 xf[4][4];
  #pragma unroll
  for (int ti = 0; ti < 4; ++ti) {
    #pragma unroll
    for (int kk = 0; kk < 4; ++kk) {
      int row = ti * 16 + li;
      int cb  = (kk * 32 + g * 8) * 2;
      xf[ti][kk] = *reinterpret_cast<const bf16x8*>(sm + XO_OFF + swz(row, cb, 256));
    }
  }

  const f32x4 zero4 = {0.f, 0.f, 0.f, 0.f};

  // --- Q,K (swapped: D = W * X^T -> Dt[d][i]): waves 0,1 -> Q ; waves 2,3 -> K
  {
    const short* wmat = wbf + ((w < 2) ? 0 : 16384);
    const float* bias = (w < 2) ? bq : bk;
    const int dbase   = (w & 1) * 64;
    const int qkbase  = (w < 2) ? Q_OFF : K_OFF;

    f32x4 acc[4][4];
    #pragma unroll
    for (int mi = 0; mi < 4; ++mi)
      #pragma unroll
      for (int ni = 0; ni < 4; ++ni) acc[mi][ni] = zero4;

    #pragma unroll
    for (int mi = 0; mi < 4; ++mi) {
      bf16x8 af[4];
      #pragma unroll
      for (int kk = 0; kk < 4; ++kk)
        af[kk] = *reinterpret_cast<const bf16x8*>(wmat + (dbase + mi * 16 + li) * CDIM + kk * 32 + g * 8);
      #pragma unroll
      for (int ni = 0; ni < 4; ++ni)
        #pragma unroll
        for (int kk = 0; kk < 4; ++kk)
          acc[mi][ni] = __builtin_amdgcn_mfma_f32_16x16x32_bf16(af[kk], xf[ni][kk], acc[mi][ni], 0, 0, 0);
    }
    // store Dt[d][i] -> Q/K [i][d] packed b64
    #pragma unroll
    for (int mi = 0; mi < 4; ++mi) {
      int d0 = dbase + mi * 16 + g * 4;
      float b0 = bias[d0 + 0], b1 = bias[d0 + 1], b2 = bias[d0 + 2], b3 = bias[d0 + 3];
      #pragma unroll
      for (int ni = 0; ni < 4; ++ni) {
        int row = ni * 16 + li;      // token i
        int cb  = d0 * 2;
        s16x4 pk;
        pk.x = f2bf(acc[mi][ni].x + b0);
        pk.y = f2bf(acc[mi][ni].y + b1);
        pk.z = f2bf(acc[mi][ni].z + b2);
        pk.w = f2bf(acc[mi][ni].w + b3);
        *reinterpret_cast<s16x4*>(sm + qkbase + swz(row, cb, 256)) = pk;
      }
    }
  }

  // --- V (normal: D = X * Wv^T -> V[i][d]): wave w covers d in [32w, 32w+32)
  {
    const short* wv_ = wbf + 32768;
    f32x4 accv[4][2];
    #pragma unroll
    for (int mi = 0; mi < 4; ++mi) { accv[mi][0] = zero4; accv[mi][1] = zero4; }
    bf16x8 bfv[2][4];
    #pragma unroll
    for (int n2 = 0; n2 < 2; ++n2)
      #pragma unroll
      for (int kk = 0; kk < 4; ++kk)
        bfv[n2][kk] = *reinterpret_cast<const bf16x8*>(wv_ + (w * 32 + n2 * 16 + li) * CDIM + kk * 32 + g * 8);
    #pragma unroll
    for (int mi = 0; mi < 4; ++mi)
      #pragma unroll
      for (int n2 = 0; n2 < 2; ++n2)
        #pragma unroll
        for (int kk = 0; kk < 4; ++kk)
          accv[mi][n2] = __builtin_amdgcn_mfma_f32_16x16x32_bf16(xf[mi][kk], bfv[n2][kk], accv[mi][n2], 0, 0, 0);
    // store V[i][d] -> Vt[d][i] packed (values r are consecutive i)
    #pragma unroll
    for (int mi = 0; mi < 4; ++mi) {
      #pragma unroll
      for (int n2 = 0; n2 < 2; ++n2) {
        int d = w * 32 + n2 * 16 + li;
        float bb = bv[d];
        int cb = (mi * 16 + g * 4) * 2;  // i0
        s16x4 pk;
        pk.x = f2bf(accv[mi][n2].x + bb);
        pk.y = f2bf(accv[mi][n2].y + bb);
        pk.z = f2bf(accv[mi][n2].z + bb);
        pk.w = f2bf(accv[mi][n2].w + bb);
        *reinterpret_cast<s16x4*>(sm + VT_OFF + swz(d, cb, 128)) = pk;
      }
    }
  }
  __syncthreads();

  // ---------- phase 2: scores (swapped: St = K * Q^T) + softmax, head h = w ----------
  const float scale = 0.17677669529663688f;  // 1/sqrt(32)
  f32x4 st[4][4];  // [mj (j-tile)][ni (i-tile)]
  {
    bf16x8 kf[4], qf[4];
    int cb = (w * 32 + g * 8) * 2;   // d-range of head w
    #pragma unroll
    for (int t = 0; t < 4; ++t) {
      int row = t * 16 + li;
      kf[t] = *reinterpret_cast<const bf16x8*>(sm + K_OFF + swz(row, cb, 256));
      qf[t] = *reinterpret_cast<const bf16x8*>(sm + Q_OFF + swz(row, cb, 256));
    }
    #pragma unroll
    for (int mj = 0; mj < 4; ++mj)
      #pragma unroll
      for (int ni = 0; ni < 4; ++ni)
        st[mj][ni] = __builtin_amdgcn_mfma_f32_16x16x32_bf16(kf[mj], qf[ni], zero4, 0, 0, 0);
  }
  // gate values per (mj, r): j = mj*16 + g*4 + r  (broadcast LDS reads)
  float gv[16];
  #pragma unroll
  for (int mj = 0; mj < 4; ++mj)
    #pragma unroll
    for (int r = 0; r < 4; ++r)
      gv[mj * 4 + r] = gate[mj * 16 + g * 4 + r];

  #pragma unroll
  for (int ni = 0; ni < 4; ++ni) {
    float mx = -3.0e38f;
    #pragma unroll
    for (int mj = 0; mj < 4; ++mj) {
      f32x4 v = st[mj][ni];
      v.x = v.x * scale + gv[mj * 4 + 0];
      v.y = v.y * scale + gv[mj * 4 + 1];
      v.z = v.z * scale + gv[mj * 4 + 2];
      v.w = v.w * scale + gv[mj * 4 + 3];
      st[mj][ni] = v;
      mx = fmaxf(mx, fmaxf(fmaxf(v.x, v.y), fmaxf(v.z, v.w)));
    }
    mx = fmaxf(mx, __shfl_xor(mx, 16));
    mx = fmaxf(mx, __shfl_xor(mx, 32));
    float sum = 0.f;
    #pragma unroll
    for (int mj = 0; mj < 4; ++mj) {
      f32x4 v = st[mj][ni];
      v.x = __expf(v.x - mx); v.y = __expf(v.y - mx);
      v.z = __expf(v.z - mx); v.w = __expf(v.w - mx);
      st[mj][ni] = v;
      sum += v.x + v.y + v.z + v.w;
    }
    sum += __shfl_xor(sum, 16);
    sum += __shfl_xor(sum, 32);
    float inv = 1.f / (sum + 1e-9f);
    #pragma unroll
    for (int mj = 0; mj < 4; ++mj) {
      st[mj][ni].x *= inv; st[mj][ni].y *= inv;
      st[mj][ni].z *= inv; st[mj][ni].w *= inv;
    }
  }
  __syncthreads();   // all waves done reading Q/K before P overwrites that region

  // store P^T regs -> P[i][j] packed b64
  const int pb = P_OFF + w * 8192;
  #pragma unroll
  for (int mj = 0; mj < 4; ++mj) {
    int cb = (mj * 16 + g * 4) * 2;  // j0
    #pragma unroll
    for (int ni = 0; ni < 4; ++ni) {
      int row = ni * 16 + li;        // token i
      s16x4 pk;
      pk.x = f2bf(st[mj][ni].x); pk.y = f2bf(st[mj][ni].y);
      pk.z = f2bf(st[mj][ni].z); pk.w = f2bf(st[mj][ni].w);
      *reinterpret_cast<s16x4*>(sm + pb + swz(row, cb, 128)) = pk;
    }
  }

  // ---------- phase 3: PV (swapped: Ot = Vt * P^T) ----------
  {
    f32x4 accO[2][4];
    #pragma unroll
    for (int md = 0; md < 2; ++md)
      #pragma unroll
      for (int ni = 0; ni < 4; ++ni) accO[md][ni] = zero4;
    bf16x8 vf[2][2];
    #pragma unroll
    for (int md = 0; md < 2; ++md)
      #pragma unroll
      for (int ks = 0; ks < 2; ++ks) {
        int row = w * 32 + md * 16 + li;   // d row in Vt
        int cb  = (ks * 32 + g * 8) * 2;   // j
        vf[md][ks] = *reinterpret_cast<const bf16x8*>(sm + VT_OFF + swz(row, cb, 128));
      }
    bf16x8 pf[4][2];
    #pragma unroll
    for (int ni = 0; ni < 4; ++ni)
      #pragma unroll
      for (int ks = 0; ks < 2; ++ks) {
        int row = ni * 16 + li;            // token i
        int cb  = (ks * 32 + g * 8) * 2;   // j
        pf[ni][ks] = *reinterpret_cast<const bf16x8*>(sm + pb + swz(row, cb, 128));
      }
    #pragma unroll
    for (int md = 0; md < 2; ++md)
      #pragma unroll
      for (int ni = 0; ni < 4; ++ni)
        #pragma unroll
        for (int ks = 0; ks < 2; ++ks)
          accO[md][ni] = __builtin_amdgcn_mfma_f32_16x16x32_bf16(vf[md][ks], pf[ni][ks], accO[md][ni], 0, 0, 0);
    // store Ot[d][i] -> O[i][d] packed (values r are consecutive d)
    #pragma unroll
    for (int md = 0; md < 2; ++md) {
      int cb = (w * 32 + md * 16 + g * 4) * 2;  // d0
      #pragma unroll
      for (int ni = 0; ni < 4; ++ni) {
        int row = ni * 16 + li;                 // token i
        s16x4 pk;
        pk.x = f2bf(accO[md][ni].x); pk.y = f2bf(accO[md][ni].y);
        pk.z = f2bf(accO[md][ni].z); pk.w = f2bf(accO[md][ni].w);
        *reinterpret_cast<s16x4*>(sm + XO_OFF + swz(row, cb, 256)) = pk;
      }
    }
  }
  __syncthreads();

  // ---------- phase 4: out-proj Y = O * Wo^T + bo ----------
  {
    const short* wo_ = wbf + 49152;
    f32x4 accY[4][2];
    #pragma unroll
    for (int mi = 0; mi < 4; ++mi) { accY[mi][0] = zero4; accY[mi][1] = zero4; }
    bf16x8 of[4][4];
    #pragma unroll
    for (int mi = 0; mi < 4; ++mi)
      #pragma unroll
      for (int kk = 0; kk < 4; ++kk) {
        int row = mi * 16 + li;
        int cb  = (kk * 32 + g * 8) * 2;
        of[mi][kk] = *reinterpret_cast<const bf16x8*>(sm + XO_OFF + swz(row, cb, 256));
      }
    bf16x8 wf[2][4];
    #pragma unroll
    for (int n2 = 0; n2 < 2; ++n2)
      #pragma unroll
      for (int kk = 0; kk < 4; ++kk)
        wf[n2][kk] = *reinterpret_cast<const bf16x8*>(wo_ + (w * 32 + n2 * 16 + li) * CDIM + kk * 32 + g * 8);
    #pragma unroll
    for (int mi = 0; mi < 4; ++mi)
      #pragma unroll
      for (int n2 = 0; n2 < 2; ++n2)
        #pragma unroll
        for (int kk = 0; kk < 4; ++kk)
          accY[mi][n2] = __builtin_amdgcn_mfma_f32_16x16x32_bf16(of[mi][kk], wf[n2][kk], accY[mi][n2], 0, 0, 0);
    float* yb = out + (size_t)b * (NTOK * CDIM);
    #pragma unroll
    for (int n2 = 0; n2 < 2; ++n2) {
      int dout = w * 32 + n2 * 16 + li;
      float bb = bo[dout];
      #pragma unroll
      for (int mi = 0; mi < 4; ++mi) {
        int i0 = mi * 16 + g * 4;
        yb[(i0 + 0) * CDIM + dout] = accY[mi][n2].x + bb;
        yb[(i0 + 1) * CDIM + dout] = accY[mi][n2].y + bb;
        yb[(i0 + 2) * CDIM + dout] = accY[mi][n2].z + bb;
        yb[(i0 + 3) * CDIM + dout] = accY[mi][n2].w + bb;
      }
    }
  }
}

extern "C" void kernel_launch(void* const* d_in, const int* in_sizes, int n_in,
                              void* d_out, int out_size, void* d_ws, size_t ws_size,
                              hipStream_t stream) {
  const float* x    = (const float*)d_in[0];
  const float* ent  = (const float*)d_in[1];
  const float* wq   = (const float*)d_in[2];
  const float* bq   = (const float*)d_in[3];
  const float* wk   = (const float*)d_in[4];
  const float* bk   = (const float*)d_in[5];
  const float* wv   = (const float*)d_in[6];
  const float* bv   = (const float*)d_in[7];
  const float* wo   = (const float*)d_in[8];
  const float* bo   = (const float*)d_in[9];
  const int*   beta = (const int*)d_in[10];

  short* wbf = (short*)d_ws;             // 4 x 128x128 bf16 = 128 KB
  const int B = in_sizes[0] / (NTOK * CDIM);

  wconv_kernel<<<64, 256, 0, stream>>>(wq, wk, wv, wo, wbf);
  fused_attn<<<B, 256, 0, stream>>>(x, ent, wbf, bq, bk, bv, bo, beta, (float*)d_out);
}

// Round 2
// 99.856 us; speedup vs baseline: 1.0829x; 1.0829x over previous
//
#include <hip/hip_runtime.h>
#include <hip/hip_bf16.h>

#define NTOK 64
#define CDIM 128

typedef __attribute__((ext_vector_type(4))) float  f32x4;
typedef __attribute__((ext_vector_type(8))) short  bf16x8;
typedef __attribute__((ext_vector_type(4))) short  s16x4;

__device__ __forceinline__ s16x4 pk4(f32x4 v) {
  // packed RTNE fp32->bf16 (compiler emits v_cvt_pk_bf16_f32)
  union { __hip_bfloat162 h[2]; s16x4 s; } u;
  u.h[0] = __float22bfloat162_rn(float2{v.x, v.y});
  u.h[1] = __float22bfloat162_rn(float2{v.z, v.w});
  return u.s;
}

__device__ __forceinline__ int swz(int row, int cb, int stride) {
  return row * stride + (cb ^ ((row & 7) << 4));
}

__global__ void wconv_kernel(const float* __restrict__ wq, const float* __restrict__ wk,
                             const float* __restrict__ wv, const float* __restrict__ wo,
                             short* __restrict__ wbf) {
  int t = (blockIdx.x * 256 + threadIdx.x) * 4;   // 16 blocks * 256 * 4 = 16384
  f32x4 a = *reinterpret_cast<const f32x4*>(wq + t);
  f32x4 b = *reinterpret_cast<const f32x4*>(wk + t);
  f32x4 c = *reinterpret_cast<const f32x4*>(wv + t);
  f32x4 d = *reinterpret_cast<const f32x4*>(wo + t);
  *reinterpret_cast<s16x4*>(wbf + t)         = pk4(a);
  *reinterpret_cast<s16x4*>(wbf + 16384 + t) = pk4(b);
  *reinterpret_cast<s16x4*>(wbf + 32768 + t) = pk4(c);
  *reinterpret_cast<s16x4*>(wbf + 49152 + t) = pk4(d);
}

// LDS regions (byte offsets), time-multiplexed:
//   A [0,16K):   X -> Q -> P(heads 0,1)
//   B [16K,32K): K -> P(heads 2,3)
//   C [32K,48K): Vt -> O
#define A_OFF    0
#define B_OFF    16384
#define C_OFF    32768
#define GATE_OFF 49152
#define SMEM_BYTES (49152 + 256)

__global__ __launch_bounds__(256, 3) void fused_attn(
    const float* __restrict__ x, const float* __restrict__ ent,
    const short* __restrict__ wbf,
    const float* __restrict__ bq, const float* __restrict__ bk,
    const float* __restrict__ bv, const float* __restrict__ bo,
    const int* __restrict__ beta, float* __restrict__ out)
{
  __shared__ unsigned char sm[SMEM_BYTES];
  float* gate = (float*)(sm + GATE_OFF);
  const int tid  = threadIdx.x;
  const int lane = tid & 63;
  const int w    = tid >> 6;        // wave id 0..3 (= head id in attn phases)
  const int g    = lane >> 4;       // 16-lane group 0..3
  const int li   = lane & 15;
  const int b    = blockIdx.x;

  // ---------- phase 0: stage X (fp32 -> bf16, swizzled) into A + gate ----------
  {
    const float* xb = x + (size_t)b * (NTOK * CDIM);
    #pragma unroll
    for (int it = 0; it < 8; ++it) {
      int f = (tid + 256 * it) * 4;
      int row = f >> 7, col = f & 127;
      f32x4 v = *reinterpret_cast<const f32x4*>(xb + f);
      *reinterpret_cast<s16x4*>(sm + A_OFF + swz(row, col * 2, 256)) = pk4(v);
    }
    if (tid < NTOK) gate[tid] = -(float)beta[0] * ent[(size_t)b * NTOK + tid];
  }
  __syncthreads();   // B0: X staged

  // Preload all X fragments (layout works as both A-op and B-op fragment)
  bf16x8 xf[4][4];
  #pragma unroll
  for (int ti = 0; ti < 4; ++ti)
    #pragma unroll
    for (int kk = 0; kk < 4; ++kk)
      xf[ti][kk] = *reinterpret_cast<const bf16x8*>(sm + A_OFF + swz(ti * 16 + li, (kk * 32 + g * 8) * 2, 256));

  __syncthreads();   // B1: all waves hold X in regs; region A may be overwritten

  const f32x4 zero4 = {0.f, 0.f, 0.f, 0.f};

  // ---------- phase 1a: V (normal: V = X * Wv^T), wave w -> d in [32w,32w+32) ----------
  {
    const short* wv_ = wbf + 32768;
    f32x4 accv[4][2];
    #pragma unroll
    for (int mi = 0; mi < 4; ++mi) { accv[mi][0] = zero4; accv[mi][1] = zero4; }
    bf16x8 bfv[2][4];
    #pragma unroll
    for (int n2 = 0; n2 < 2; ++n2)
      #pragma unroll
      for (int kk = 0; kk < 4; ++kk)
        bfv[n2][kk] = *reinterpret_cast<const bf16x8*>(wv_ + (w * 32 + n2 * 16 + li) * CDIM + kk * 32 + g * 8);
    #pragma unroll
    for (int mi = 0; mi < 4; ++mi)
      #pragma unroll
      for (int n2 = 0; n2 < 2; ++n2)
        #pragma unroll
        for (int kk = 0; kk < 4; ++kk)
          accv[mi][n2] = __builtin_amdgcn_mfma_f32_16x16x32_bf16(xf[mi][kk], bfv[n2][kk], accv[mi][n2], 0, 0, 0);
    // store V[i][d] -> Vt[d][i] in C (values r are consecutive i)
    #pragma unroll
    for (int mi = 0; mi < 4; ++mi)
      #pragma unroll
      for (int n2 = 0; n2 < 2; ++n2) {
        int d = w * 32 + n2 * 16 + li;
        float bb = bv[d];
        f32x4 v = accv[mi][n2];
        v.x += bb; v.y += bb; v.z += bb; v.w += bb;
        *reinterpret_cast<s16x4*>(sm + C_OFF + swz(d, (mi * 16 + g * 4) * 2, 128)) = pk4(v);
      }
  }

  // ---------- phase 1b: Q,K (swapped: Dt = W * X^T), streamed per 16-dout tile ----------
  // waves 0,1 -> Q into A ; waves 2,3 -> K into B
  {
    const short* wmat = wbf + ((w < 2) ? 0 : 16384);
    const float* bias = (w < 2) ? bq : bk;
    const int dbase   = (w & 1) * 64;
    const int qkoff   = (w < 2) ? A_OFF : B_OFF;

    #pragma unroll
    for (int mi = 0; mi < 4; ++mi) {
      bf16x8 af[4];
      #pragma unroll
      for (int kk = 0; kk < 4; ++kk)
        af[kk] = *reinterpret_cast<const bf16x8*>(wmat + (dbase + mi * 16 + li) * CDIM + kk * 32 + g * 8);
      f32x4 acc[4];
      #pragma unroll
      for (int ni = 0; ni < 4; ++ni) acc[ni] = zero4;
      #pragma unroll
      for (int ni = 0; ni < 4; ++ni)
        #pragma unroll
        for (int kk = 0; kk < 4; ++kk)
          acc[ni] = __builtin_amdgcn_mfma_f32_16x16x32_bf16(af[kk], xf[ni][kk], acc[ni], 0, 0, 0);
      int d0 = dbase + mi * 16 + g * 4;
      float4 b4 = *reinterpret_cast<const float4*>(bias + d0);
      #pragma unroll
      for (int ni = 0; ni < 4; ++ni) {
        f32x4 v = acc[ni];
        v.x += b4.x; v.y += b4.y; v.z += b4.z; v.w += b4.w;
        *reinterpret_cast<s16x4*>(sm + qkoff + swz(ni * 16 + li, d0 * 2, 256)) = pk4(v);
      }
    }
  }
  __syncthreads();   // B2: Q,K,Vt ready

  // ---------- phase 2: scores (swapped: St = K * Q^T) + softmax, head h = w ----------
  const float scale = 0.17677669529663688f;  // 1/sqrt(32)
  f32x4 st[4][4];  // [mj (j-tile)][ni (i-tile)]
  {
    bf16x8 kf[4], qf[4];
    int cb = (w * 32 + g * 8) * 2;   // d-range of head w
    #pragma unroll
    for (int t = 0; t < 4; ++t) {
      kf[t] = *reinterpret_cast<const bf16x8*>(sm + B_OFF + swz(t * 16 + li, cb, 256));
      qf[t] = *reinterpret_cast<const bf16x8*>(sm + A_OFF + swz(t * 16 + li, cb, 256));
    }
    #pragma unroll
    for (int mj = 0; mj < 4; ++mj)
      #pragma unroll
      for (int ni = 0; ni < 4; ++ni)
        st[mj][ni] = __builtin_amdgcn_mfma_f32_16x16x32_bf16(kf[mj], qf[ni], zero4, 0, 0, 0);
  }
  float gv[16];
  #pragma unroll
  for (int mj = 0; mj < 4; ++mj)
    #pragma unroll
    for (int r = 0; r < 4; ++r)
      gv[mj * 4 + r] = gate[mj * 16 + g * 4 + r];

  #pragma unroll
  for (int ni = 0; ni < 4; ++ni) {
    float mx = -3.0e38f;
    #pragma unroll
    for (int mj = 0; mj < 4; ++mj) {
      f32x4 v = st[mj][ni];
      v.x = v.x * scale + gv[mj * 4 + 0];
      v.y = v.y * scale + gv[mj * 4 + 1];
      v.z = v.z * scale + gv[mj * 4 + 2];
      v.w = v.w * scale + gv[mj * 4 + 3];
      st[mj][ni] = v;
      mx = fmaxf(mx, fmaxf(fmaxf(v.x, v.y), fmaxf(v.z, v.w)));
    }
    mx = fmaxf(mx, __shfl_xor(mx, 16));
    mx = fmaxf(mx, __shfl_xor(mx, 32));
    float sum = 0.f;
    #pragma unroll
    for (int mj = 0; mj < 4; ++mj) {
      f32x4 v = st[mj][ni];
      v.x = __expf(v.x - mx); v.y = __expf(v.y - mx);
      v.z = __expf(v.z - mx); v.w = __expf(v.w - mx);
      st[mj][ni] = v;
      sum += v.x + v.y + v.z + v.w;
    }
    sum += __shfl_xor(sum, 16);
    sum += __shfl_xor(sum, 32);
    float inv = 1.f / (sum + 1e-9f);
    #pragma unroll
    for (int mj = 0; mj < 4; ++mj) {
      st[mj][ni].x *= inv; st[mj][ni].y *= inv;
      st[mj][ni].z *= inv; st[mj][ni].w *= inv;
    }
  }
  __syncthreads();   // B3: all waves done reading Q/K; P may overwrite A/B

  // store P^T regs -> P[i][j] (head w at sm + w*8K, spans A then B)
  unsigned char* pb = sm + w * 8192;
  #pragma unroll
  for (int mj = 0; mj < 4; ++mj) {
    int cb = (mj * 16 + g * 4) * 2;  // j0
    #pragma unroll
    for (int ni = 0; ni < 4; ++ni)
      *reinterpret_cast<s16x4*>(pb + swz(ni * 16 + li, cb, 128)) = pk4(st[mj][ni]);
  }

  // ---------- phase 3: PV (swapped: Ot = Vt * P^T) ----------
  {
    f32x4 accO[2][4];
    #pragma unroll
    for (int md = 0; md < 2; ++md)
      #pragma unroll
      for (int ni = 0; ni < 4; ++ni) accO[md][ni] = zero4;
    bf16x8 vf[2][2];
    #pragma unroll
    for (int md = 0; md < 2; ++md)
      #pragma unroll
      for (int ks = 0; ks < 2; ++ks)
        vf[md][ks] = *reinterpret_cast<const bf16x8*>(sm + C_OFF + swz(w * 32 + md * 16 + li, (ks * 32 + g * 8) * 2, 128));
    bf16x8 pf[4][2];
    #pragma unroll
    for (int ni = 0; ni < 4; ++ni)
      #pragma unroll
      for (int ks = 0; ks < 2; ++ks)
        pf[ni][ks] = *reinterpret_cast<const bf16x8*>(pb + swz(ni * 16 + li, (ks * 32 + g * 8) * 2, 128));
    #pragma unroll
    for (int md = 0; md < 2; ++md)
      #pragma unroll
      for (int ni = 0; ni < 4; ++ni)
        #pragma unroll
        for (int ks = 0; ks < 2; ++ks)
          accO[md][ni] = __builtin_amdgcn_mfma_f32_16x16x32_bf16(vf[md][ks], pf[ni][ks], accO[md][ni], 0, 0, 0);
    __syncthreads();   // B4: all waves done reading Vt; O may overwrite C
    // store Ot[d][i] -> O[i][d] in C (values r are consecutive d)
    #pragma unroll
    for (int md = 0; md < 2; ++md) {
      int cb = (w * 32 + md * 16 + g * 4) * 2;  // d0
      #pragma unroll
      for (int ni = 0; ni < 4; ++ni)
        *reinterpret_cast<s16x4*>(sm + C_OFF + swz(ni * 16 + li, cb, 256)) = pk4(accO[md][ni]);
    }
  }
  __syncthreads();   // B5: O ready

  // ---------- phase 4: out-proj swapped (Yt = Wo * O^T) -> float4 stores ----------
  {
    const short* wo_ = wbf + 49152;
    f32x4 accY[2][4];   // [mi (dout tile)][ni (i tile)]
    #pragma unroll
    for (int mi = 0; mi < 2; ++mi)
      #pragma unroll
      for (int ni = 0; ni < 4; ++ni) accY[mi][ni] = zero4;
    bf16x8 wfa[2][4];
    #pragma unroll
    for (int mi = 0; mi < 2; ++mi)
      #pragma unroll
      for (int kk = 0; kk < 4; ++kk)
        wfa[mi][kk] = *reinterpret_cast<const bf16x8*>(wo_ + (w * 32 + mi * 16 + li) * CDIM + kk * 32 + g * 8);
    bf16x8 of[4][4];
    #pragma unroll
    for (int ni = 0; ni < 4; ++ni)
      #pragma unroll
      for (int kk = 0; kk < 4; ++kk)
        of[ni][kk] = *reinterpret_cast<const bf16x8*>(sm + C_OFF + swz(ni * 16 + li, (kk * 32 + g * 8) * 2, 256));
    #pragma unroll
    for (int mi = 0; mi < 2; ++mi)
      #pragma unroll
      for (int ni = 0; ni < 4; ++ni)
        #pragma unroll
        for (int kk = 0; kk < 4; ++kk)
          accY[mi][ni] = __builtin_amdgcn_mfma_f32_16x16x32_bf16(wfa[mi][kk], of[ni][kk], accY[mi][ni], 0, 0, 0);
    float* yb = out + (size_t)b * (NTOK * CDIM);
    #pragma unroll
    for (int mi = 0; mi < 2; ++mi) {
      int dout0 = w * 32 + mi * 16 + g * 4;
      float4 bo4 = *reinterpret_cast<const float4*>(bo + dout0);
      #pragma unroll
      for (int ni = 0; ni < 4; ++ni) {
        int i = ni * 16 + li;
        f32x4 y = accY[mi][ni];
        y.x += bo4.x; y.y += bo4.y; y.z += bo4.z; y.w += bo4.w;
        *reinterpret_cast<f32x4*>(yb + i * CDIM + dout0) = y;
      }
    }
  }
}

extern "C" void kernel_launch(void* const* d_in, const int* in_sizes, int n_in,
                              void* d_out, int out_size, void* d_ws, size_t ws_size,
                              hipStream_t stream) {
  const float* x    = (const float*)d_in[0];
  const float* ent  = (const float*)d_in[1];
  const float* wq   = (const float*)d_in[2];
  const float* bq   = (const float*)d_in[3];
  const float* wk   = (const float*)d_in[4];
  const float* bk   = (const float*)d_in[5];
  const float* wv   = (const float*)d_in[6];
  const float* bv   = (const float*)d_in[7];
  const float* wo   = (const float*)d_in[8];
  const float* bo   = (const float*)d_in[9];
  const int*   beta = (const int*)d_in[10];

  short* wbf = (short*)d_ws;             // 4 x 128x128 bf16 = 128 KB
  const int B = in_sizes[0] / (NTOK * CDIM);

  wconv_kernel<<<16, 256, 0, stream>>>(wq, wk, wv, wo, wbf);
  fused_attn<<<B, 256, 0, stream>>>(x, ent, wbf, bq, bk, bv, bo, beta, (float*)d_out);
}